// Round 7
// baseline (1886.668 us; speedup 1.0000x reference)
//
#include <hip/hip_runtime.h>
#include <cfloat>
#include <cstdint>

// VQ-VAE vector quantizer forward. Round 7: 2-product split-bf16 in argmin
// (s = ee - 2*zh.(eh+el); zl term dropped, eps widened to 0.035 so the fp64
// rescue net guarantees exact indices), 24KB LDS + launch_bounds(256,4) for
// 4 blocks/CU; proj_out also 2-product (wo_lo dropped).
#define B_      16
#define DIN     512
#define HW      1024
#define CDIM    256
#define KCODES  8192
#define NTOK    (B_ * HW)            // 16384
#define OUT_ELEMS (B_ * DIN * HW)    // 8388608
#define GAP_EPS 0.035f
#define NSTRIP  8
#define NPART   (NSTRIP * 2)
#define CPS     (KCODES / NSTRIP)    // 1024
#define MAXR    4096
#define RCHUNK  32
#define RBLOCKS 2048
#define LOSS_SCALE (1.0f / ((float)NTOK * (float)CDIM))

typedef __attribute__((ext_vector_type(8))) short bf16x8;
typedef __attribute__((ext_vector_type(4))) float f32x4;

static __device__ __forceinline__ short f2bf(float f) {
  unsigned u = __builtin_bit_cast(unsigned, f);
  u += 0x7FFFu + ((u >> 16) & 1u);           // RNE
  return (short)(u >> 16);
}
static __device__ __forceinline__ float bf2f(short h) {
  unsigned u = ((unsigned)(unsigned short)h) << 16;
  return __builtin_bit_cast(float, u);
}

#define GLL16(gsrc, ldst)                                                      \
  __builtin_amdgcn_global_load_lds(                                            \
      (const __attribute__((address_space(1))) unsigned int*)(gsrc),           \
      (__attribute__((address_space(3))) unsigned int*)(ldst), 16, 0, 0)

// ---------------- K0: fused prep: cb hi/lo + ee | W hi/lo | xT hi/lo ---------
#define PREP_CB_BLKS 2048
#define PREP_W_BLKS  128
#define PREP_X_BLKS  2048
__global__ __launch_bounds__(256) void k_prep(
    const float* __restrict__ cb, const float* __restrict__ Win,
    const float* __restrict__ Wout, const float* __restrict__ x,
    short* __restrict__ cb_hi, short* __restrict__ cb_lo, float* __restrict__ ee,
    short* __restrict__ wi_hi, short* __restrict__ wi_lo,
    short* __restrict__ wo_hi,
    short* __restrict__ xT_hi, short* __restrict__ xT_lo,
    float* __restrict__ loss, int* __restrict__ rcount) {
  __shared__ float T[64][65];
  const int blk = blockIdx.x;
  const int tid = threadIdx.x;
  if (blk == 0 && tid < 2) {
    if (tid == 0) *loss = 0.0f; else *rcount = 0;
  }
  if (blk < PREP_CB_BLKS) {
    const int wid = (blk * 256 + tid) >> 6;
    const int lane = tid & 63;
    const float4 v = *(const float4*)(cb + (size_t)wid * CDIM + lane * 4);
    float s = v.x * v.x + v.y * v.y + v.z * v.z + v.w * v.w;
    short4 h, l;
    h.x = f2bf(v.x); l.x = f2bf(v.x - bf2f(h.x));
    h.y = f2bf(v.y); l.y = f2bf(v.y - bf2f(h.y));
    h.z = f2bf(v.z); l.z = f2bf(v.z - bf2f(h.z));
    h.w = f2bf(v.w); l.w = f2bf(v.w - bf2f(h.w));
    *(short4*)(cb_hi + (size_t)wid * CDIM + lane * 4) = h;
    *(short4*)(cb_lo + (size_t)wid * CDIM + lane * 4) = l;
#pragma unroll
    for (int off = 32; off > 0; off >>= 1) s += __shfl_down(s, off, 64);
    if (lane == 0) ee[wid] = s;
  } else if (blk < PREP_CB_BLKS + PREP_W_BLKS) {
    const int i = ((blk - PREP_CB_BLKS) * 256 + tid) * 4;
    {
      const float4 v = *(const float4*)(Win + i);
      short4 h, l;
      h.x = f2bf(v.x); l.x = f2bf(v.x - bf2f(h.x));
      h.y = f2bf(v.y); l.y = f2bf(v.y - bf2f(h.y));
      h.z = f2bf(v.z); l.z = f2bf(v.z - bf2f(h.z));
      h.w = f2bf(v.w); l.w = f2bf(v.w - bf2f(h.w));
      *(short4*)(wi_hi + i) = h; *(short4*)(wi_lo + i) = l;
    }
    {
      const float4 v = *(const float4*)(Wout + i);
      short4 h;
      h.x = f2bf(v.x); h.y = f2bf(v.y); h.z = f2bf(v.z); h.w = f2bf(v.w);
      *(short4*)(wo_hi + i) = h;
    }
  } else {
    const int id = blk - PREP_CB_BLKS - PREP_W_BLKS;
    const int xb = id & 255, yb = id >> 8;
    const int b = xb >> 4;
    const int hw0 = (xb & 15) * 64;
    const int din0 = yb * 64;
    {
      const int r = tid >> 2;
      const int c = tid & 3;
      const float* src = x + ((size_t)b * DIN + din0 + r) * HW + hw0 + c * 16;
#pragma unroll
      for (int j = 0; j < 4; ++j) {
        const float4 v = *(const float4*)(src + j * 4);
        T[r][c * 16 + j * 4 + 0] = v.x;
        T[r][c * 16 + j * 4 + 1] = v.y;
        T[r][c * 16 + j * 4 + 2] = v.z;
        T[r][c * 16 + j * 4 + 3] = v.w;
      }
    }
    __syncthreads();
    {
      const int tt = tid & 63;
      const int c2 = tid >> 6;
      short h[16], l[16];
#pragma unroll
      for (int j = 0; j < 16; ++j) {
        const float f = T[c2 * 16 + j][tt];
        h[j] = f2bf(f); l[j] = f2bf(f - bf2f(h[j]));
      }
      const size_t base = ((size_t)b * HW + hw0 + tt) * DIN + din0 + c2 * 16;
      *(bf16x8*)(xT_hi + base)     = *(bf16x8*)&h[0];
      *(bf16x8*)(xT_hi + base + 8) = *(bf16x8*)&h[8];
      *(bf16x8*)(xT_lo + base)     = *(bf16x8*)&l[0];
      *(bf16x8*)(xT_lo + base + 8) = *(bf16x8*)&l[8];
    }
  }
}

// ---------------- K1: proj_in MFMA: z = xT @ Win^T + b_in (3-product) ---------
__global__ __launch_bounds__(256, 2) void k_proj_in_mfma(
    const short* __restrict__ xT_hi, const short* __restrict__ xT_lo,
    const short* __restrict__ wi_hi, const short* __restrict__ wi_lo,
    const float* __restrict__ bin,
    short* __restrict__ z_hi, short* __restrict__ z_lo) {
  __shared__ short lds_s[4 * 128 * 32];
  char* ldsc = (char*)lds_s;
  const int tid = threadIdx.x;
  const int w = tid >> 6, lane = tid & 63;
  const int quad = lane >> 4, l16 = lane & 15;
  const int wm = w >> 1, wn = w & 1;
  const int tok0 = blockIdx.x * 128;
  const int cd0 = blockIdx.y * 128;

  const int uA = (w << 6) + lane, uB = uA + 256;
  const int tA = uA >> 2, pA = uA & 3, qA = pA ^ ((tA >> 1) & 3);
  const int tB = uB >> 2, pB = uB & 3, qB = pB ^ ((tB >> 1) & 3);
  const int offA = tA * DIN + qA * 8;
  const int offB = tB * DIN + qB * 8;
  const short* gAh0 = xT_hi + (size_t)tok0 * DIN + offA;
  const short* gAh1 = xT_hi + (size_t)tok0 * DIN + offB;
  const short* gAl0 = xT_lo + (size_t)tok0 * DIN + offA;
  const short* gAl1 = xT_lo + (size_t)tok0 * DIN + offB;
  const short* gBh0 = wi_hi + (size_t)cd0 * DIN + offA;
  const short* gBh1 = wi_hi + (size_t)cd0 * DIN + offB;
  const short* gBl0 = wi_lo + (size_t)cd0 * DIN + offA;
  const short* gBl1 = wi_lo + (size_t)cd0 * DIN + offB;

  int aoffs[4], boffs[4];
#pragma unroll
  for (int mi = 0; mi < 4; ++mi) {
    const int t = wm * 64 + mi * 16 + l16;
    aoffs[mi] = t * 64 + (quad ^ ((t >> 1) & 3)) * 16;
  }
#pragma unroll
  for (int ni = 0; ni < 4; ++ni) {
    const int t = wn * 64 + ni * 16 + l16;
    boffs[ni] = 16384 + t * 64 + (quad ^ ((t >> 1) & 3)) * 16;
  }

  f32x4 acc[4][4];
#pragma unroll
  for (int mi = 0; mi < 4; ++mi)
#pragma unroll
    for (int ni = 0; ni < 4; ++ni) acc[mi][ni] = (f32x4){0.f, 0.f, 0.f, 0.f};

  for (int kb = 0; kb < DIN; kb += 32) {
    __syncthreads();
    GLL16(gAh0 + kb, ldsc + ((0 * 4 + w) << 10));
    GLL16(gAh1 + kb, ldsc + ((1 * 4 + w) << 10));
    GLL16(gAl0 + kb, ldsc + ((2 * 4 + w) << 10));
    GLL16(gAl1 + kb, ldsc + ((3 * 4 + w) << 10));
    GLL16(gBh0 + kb, ldsc + ((4 * 4 + w) << 10));
    GLL16(gBh1 + kb, ldsc + ((5 * 4 + w) << 10));
    GLL16(gBl0 + kb, ldsc + ((6 * 4 + w) << 10));
    GLL16(gBl1 + kb, ldsc + ((7 * 4 + w) << 10));
    __syncthreads();
    bf16x8 ah[4], al[4], bh[4], bl[4];
#pragma unroll
    for (int mi = 0; mi < 4; ++mi) {
      ah[mi] = *(const bf16x8*)(ldsc + aoffs[mi]);
      al[mi] = *(const bf16x8*)(ldsc + 8192 + aoffs[mi]);
    }
#pragma unroll
    for (int ni = 0; ni < 4; ++ni) {
      bh[ni] = *(const bf16x8*)(ldsc + boffs[ni]);
      bl[ni] = *(const bf16x8*)(ldsc + 8192 + boffs[ni]);
    }
#pragma unroll
    for (int mi = 0; mi < 4; ++mi)
#pragma unroll
      for (int ni = 0; ni < 4; ++ni) {
        f32x4 c = acc[mi][ni];
        c = __builtin_amdgcn_mfma_f32_16x16x32_bf16(ah[mi], bh[ni], c, 0, 0, 0);
        c = __builtin_amdgcn_mfma_f32_16x16x32_bf16(ah[mi], bl[ni], c, 0, 0, 0);
        c = __builtin_amdgcn_mfma_f32_16x16x32_bf16(al[mi], bh[ni], c, 0, 0, 0);
        acc[mi][ni] = c;
      }
  }
  float bv[4];
#pragma unroll
  for (int ni = 0; ni < 4; ++ni) bv[ni] = bin[cd0 + wn * 64 + ni * 16 + l16];
#pragma unroll
  for (int mi = 0; mi < 4; ++mi)
#pragma unroll
    for (int r = 0; r < 4; ++r) {
      const int t = tok0 + wm * 64 + mi * 16 + quad * 4 + r;
#pragma unroll
      for (int ni = 0; ni < 4; ++ni) {
        const int cd = cd0 + wn * 64 + ni * 16 + l16;
        const float o = acc[mi][ni][r] + bv[ni];
        const short h = f2bf(o);
        z_hi[(size_t)t * CDIM + cd] = h;
        z_lo[(size_t)t * CDIM + cd] = f2bf(o - bf2f(h));
      }
    }
}

// ---------------- K2: MFMA distance GEMM + argmin (2-product) -----------------
// s = ee - 2*zh.(eh+el); zl term dropped (|err| <~ 6e-3 << GAP_EPS; rescue
// net makes indices exact). LDS: Ah | Bh | Bl, 24 KB -> 4+ blocks/CU.
__global__ __launch_bounds__(256, 4) void k_argmin_mfma(
    const short* __restrict__ z_hi,
    const short* __restrict__ cb_hi, const short* __restrict__ cb_lo,
    const float* __restrict__ ee,
    float* __restrict__ pmv, int* __restrict__ pmi, float* __restrict__ psv) {
  __shared__ short lds_s[3 * 128 * 32];          // 24 KB
  char* ldsc = (char*)lds_s;
  const int tid = threadIdx.x;
  const int w = tid >> 6, lane = tid & 63;
  const int quad = lane >> 4, l16 = lane & 15;
  const int wm = w >> 1, wn = w & 1;
  const int tok0 = blockIdx.x * 128;
  const int cbase = blockIdx.y * CPS;

  const int uA = (w << 6) + lane, uB = uA + 256;
  const int tA = uA >> 2, pA = uA & 3, qA = pA ^ ((tA >> 1) & 3);
  const int tB = uB >> 2, pB = uB & 3, qB = pB ^ ((tB >> 1) & 3);
  const int offA = tA * CDIM + qA * 8;
  const int offB = tB * CDIM + qB * 8;
  const short* gAh0 = z_hi + (size_t)tok0 * CDIM + offA;
  const short* gAh1 = z_hi + (size_t)tok0 * CDIM + offB;

  int aoffs[4], boffs[4];
#pragma unroll
  for (int mi = 0; mi < 4; ++mi) {
    const int t = wm * 64 + mi * 16 + l16;
    aoffs[mi] = t * 64 + (quad ^ ((t >> 1) & 3)) * 16;
  }
#pragma unroll
  for (int ni = 0; ni < 4; ++ni) {
    const int t = wn * 64 + ni * 16 + l16;
    boffs[ni] = 8192 + t * 64 + (quad ^ ((t >> 1) & 3)) * 16;   // Bh base 8 KB
  }

  float mv[16], sv[16]; int bidx[16];
#pragma unroll
  for (int j = 0; j < 16; ++j) { mv[j] = FLT_MAX; sv[j] = FLT_MAX; bidx[j] = 0; }

  for (int ct = 0; ct < CPS / 128; ++ct) {
    const int ctile = cbase + ct * 128;
    const short* gBh0 = cb_hi + (size_t)ctile * CDIM + offA;
    const short* gBh1 = cb_hi + (size_t)ctile * CDIM + offB;
    const short* gBl0 = cb_lo + (size_t)ctile * CDIM + offA;
    const short* gBl1 = cb_lo + (size_t)ctile * CDIM + offB;
    f32x4 acc[4][4];
#pragma unroll
    for (int mi = 0; mi < 4; ++mi)
#pragma unroll
      for (int ni = 0; ni < 4; ++ni) acc[mi][ni] = (f32x4){0.f, 0.f, 0.f, 0.f};

    for (int kb = 0; kb < CDIM; kb += 32) {
      __syncthreads();
      GLL16(gAh0 + kb, ldsc + ((0 * 4 + w) << 10));
      GLL16(gAh1 + kb, ldsc + ((1 * 4 + w) << 10));
      GLL16(gBh0 + kb, ldsc + ((2 * 4 + w) << 10));
      GLL16(gBh1 + kb, ldsc + ((3 * 4 + w) << 10));
      GLL16(gBl0 + kb, ldsc + ((4 * 4 + w) << 10));
      GLL16(gBl1 + kb, ldsc + ((5 * 4 + w) << 10));
      __syncthreads();
      bf16x8 ah[4], bh[4], bl[4];
#pragma unroll
      for (int mi = 0; mi < 4; ++mi)
        ah[mi] = *(const bf16x8*)(ldsc + aoffs[mi]);
#pragma unroll
      for (int ni = 0; ni < 4; ++ni) {
        bh[ni] = *(const bf16x8*)(ldsc + boffs[ni]);
        bl[ni] = *(const bf16x8*)(ldsc + 8192 + boffs[ni]);
      }
#pragma unroll
      for (int mi = 0; mi < 4; ++mi)
#pragma unroll
        for (int ni = 0; ni < 4; ++ni) {
          f32x4 c = acc[mi][ni];
          c = __builtin_amdgcn_mfma_f32_16x16x32_bf16(ah[mi], bh[ni], c, 0, 0, 0);
          c = __builtin_amdgcn_mfma_f32_16x16x32_bf16(ah[mi], bl[ni], c, 0, 0, 0);
          acc[mi][ni] = c;
        }
    }
    float eev[4];
#pragma unroll
    for (int ni = 0; ni < 4; ++ni) eev[ni] = ee[ctile + wn * 64 + ni * 16 + l16];
    const int cb2 = ctile + wn * 64 + l16;
#pragma unroll
    for (int mi = 0; mi < 4; ++mi)
#pragma unroll
      for (int r = 0; r < 4; ++r) {
        const int j = mi * 4 + r;
#pragma unroll
        for (int ni = 0; ni < 4; ++ni) {
          const float s = fmaf(-2.0f, acc[mi][ni][r], eev[ni]);
          sv[j] = fminf(sv[j], fmaxf(mv[j], s));
          if (s < mv[j]) { mv[j] = s; bidx[j] = cb2 + ni * 16; }
        }
      }
  }
#pragma unroll
  for (int off = 1; off < 16; off <<= 1) {
#pragma unroll
    for (int j = 0; j < 16; ++j) {
      const float ov = __shfl_xor(mv[j], off, 64);
      const int   oi = __shfl_xor(bidx[j], off, 64);
      const float os = __shfl_xor(sv[j], off, 64);
      const float snew = fminf(fminf(sv[j], os), fmaxf(mv[j], ov));
      if (ov < mv[j] || (ov == mv[j] && oi < bidx[j])) { mv[j] = ov; bidx[j] = oi; }
      sv[j] = snew;
    }
  }
  if (l16 == 0) {
    const int strip = blockIdx.y * 2 + wn;
#pragma unroll
    for (int j = 0; j < 16; ++j) {
      const int mi = j >> 2, r = j & 3;
      const int t = tok0 + wm * 64 + mi * 16 + quad * 4 + r;
      const size_t o = (size_t)strip * NTOK + t;
      pmv[o] = mv[j]; pmi[o] = bidx[j]; psv[o] = sv[j];
    }
  }
}

// ---------------- K2b: merge 16 partials + provisional loss (fused) -----------
__global__ __launch_bounds__(256) void k_merge_loss(
    const float* __restrict__ pmv, const int* __restrict__ pmi,
    const float* __restrict__ psv,
    const short* __restrict__ z_hi, const short* __restrict__ z_lo,
    const float* __restrict__ cb,
    int* __restrict__ idxi, float* __restrict__ idx_f,
    int* __restrict__ rlist, int* __restrict__ rcount,
    float* __restrict__ loss) {
  __shared__ float lpart[4];
  const int tid = threadIdx.x;
  const int wv = tid >> 6, lane = tid & 63;
  const int t = blockIdx.x * 4 + wv;
  float mv = FLT_MAX, sv = FLT_MAX; int mi = 0x7fffffff;
  if (lane < NPART) {
    mv = pmv[(size_t)lane * NTOK + t];
    mi = pmi[(size_t)lane * NTOK + t];
    sv = psv[(size_t)lane * NTOK + t];
  }
#pragma unroll
  for (int off = 1; off < 16; off <<= 1) {
    const float ov = __shfl_xor(mv, off, 64);
    const int   oi = __shfl_xor(mi, off, 64);
    const float os = __shfl_xor(sv, off, 64);
    const float snew = fminf(fminf(sv, os), fmaxf(mv, ov));
    if (ov < mv || (ov == mv && oi < mi)) { mv = ov; mi = oi; }
    sv = snew;
  }
  const int mif = __shfl(mi, 0, 64);
  const short4 h4 = *(const short4*)(z_hi + (size_t)t * CDIM + lane * 4);
  const short4 l4 = *(const short4*)(z_lo + (size_t)t * CDIM + lane * 4);
  const float4 qv = *(const float4*)(cb + (size_t)mif * CDIM + lane * 4);
  const float dx = qv.x - (bf2f(h4.x) + bf2f(l4.x));
  const float dy = qv.y - (bf2f(h4.y) + bf2f(l4.y));
  const float dz = qv.z - (bf2f(h4.z) + bf2f(l4.z));
  const float dw = qv.w - (bf2f(h4.w) + bf2f(l4.w));
  float s = dx * dx + dy * dy + dz * dz + dw * dw;
#pragma unroll
  for (int off = 32; off > 0; off >>= 1) s += __shfl_down(s, off, 64);
  if (lane == 0) {
    idxi[t] = mif;
    idx_f[t] = (float)mif;
    lpart[wv] = s;
    if (sv - mv < GAP_EPS) {
      const int pos = atomicAdd(rcount, 1);
      if (pos < MAXR) rlist[pos] = t;
    }
  }
  __syncthreads();
  if (tid == 0) {
    atomicAdd(loss, (lpart[0] + lpart[1] + lpart[2] + lpart[3]) * LOSS_SCALE);
  }
}

// ---------------- K2c: chunked fp64 rescore -----------------------------------
__global__ __launch_bounds__(256) void k_rescue_chunk(
    const short* __restrict__ z_hi, const short* __restrict__ z_lo,
    const float* __restrict__ cb,
    const int* __restrict__ rlist, const int* __restrict__ rcount,
    double* __restrict__ slotv, int* __restrict__ sloti) {
  const int cnt0 = *rcount;
  const int cnt = cnt0 < MAXR ? cnt0 : MAXR;
  const int li0 = blockIdx.x >> 5;
  const int chunk = blockIdx.x & (RCHUNK - 1);
  if (li0 >= cnt) return;
  __shared__ float zrow[CDIM];
  __shared__ double rv[256];
  __shared__ int ri[256];
  const int tid = threadIdx.x;
  for (int li = li0; li < cnt; li += RBLOCKS / RCHUNK) {
    const int t = rlist[li];
    zrow[tid] = bf2f(z_hi[(size_t)t * CDIM + tid]) + bf2f(z_lo[(size_t)t * CDIM + tid]);
    __syncthreads();
    const int k = chunk * 256 + tid;
    const float* e = cb + (size_t)k * CDIM;
    double s0 = 0.0, s1 = 0.0, s2 = 0.0, s3 = 0.0;
    for (int c = 0; c < CDIM; c += 4) {
      const double d0 = (double)zrow[c]     - (double)e[c];
      const double d1 = (double)zrow[c + 1] - (double)e[c + 1];
      const double d2 = (double)zrow[c + 2] - (double)e[c + 2];
      const double d3 = (double)zrow[c + 3] - (double)e[c + 3];
      s0 += d0 * d0; s1 += d1 * d1; s2 += d2 * d2; s3 += d3 * d3;
    }
    rv[tid] = (s0 + s1) + (s2 + s3);
    ri[tid] = k;
    __syncthreads();
    for (int off = 128; off > 0; off >>= 1) {
      if (tid < off) {
        if (rv[tid + off] < rv[tid] ||
            (rv[tid + off] == rv[tid] && ri[tid + off] < ri[tid])) {
          rv[tid] = rv[tid + off]; ri[tid] = ri[tid + off];
        }
      }
      __syncthreads();
    }
    if (tid == 0) {
      slotv[(size_t)li * RCHUNK + chunk] = rv[0];
      sloti[(size_t)li * RCHUNK + chunk] = ri[0];
    }
    __syncthreads();
  }
}

// ---------------- K2d: fold chunk slots, patch indices + loss delta -----------
__global__ __launch_bounds__(256) void k_rescue_fin(
    const double* __restrict__ slotv, const int* __restrict__ sloti,
    const int* __restrict__ rlist, const int* __restrict__ rcount,
    const short* __restrict__ z_hi, const short* __restrict__ z_lo,
    const float* __restrict__ cb,
    int* __restrict__ idxi, float* __restrict__ idx_f, float* __restrict__ loss) {
  const int cnt0 = *rcount;
  const int cnt = cnt0 < MAXR ? cnt0 : MAXR;
  const int tid = threadIdx.x;
  const int wv = tid >> 6, lane = tid & 63;
  for (int li = wv; li < cnt; li += 4) {
    double bv = 1e300; int bx = 0x7fffffff;
    if (lane < RCHUNK) {
      bv = slotv[(size_t)li * RCHUNK + lane];
      bx = sloti[(size_t)li * RCHUNK + lane];
    }
#pragma unroll
    for (int off = 1; off < 32; off <<= 1) {
      const double ov = __shfl_xor(bv, off, 64);
      const int   oi = __shfl_xor(bx, off, 64);
      if (ov < bv || (ov == bv && oi < bx)) { bv = ov; bx = oi; }
    }
    const int newi = __shfl(bx, 0, 64);
    const int t = rlist[li];
    const int oldi = idxi[t];
    if (newi != oldi) {
      const short4 h4 = *(const short4*)(z_hi + (size_t)t * CDIM + lane * 4);
      const short4 l4 = *(const short4*)(z_lo + (size_t)t * CDIM + lane * 4);
      const float4 qn = *(const float4*)(cb + (size_t)newi * CDIM + lane * 4);
      const float4 qo = *(const float4*)(cb + (size_t)oldi * CDIM + lane * 4);
      const float zx = bf2f(h4.x) + bf2f(l4.x);
      const float zy = bf2f(h4.y) + bf2f(l4.y);
      const float zz = bf2f(h4.z) + bf2f(l4.z);
      const float zw = bf2f(h4.w) + bf2f(l4.w);
      float d = (qn.x - zx) * (qn.x - zx) - (qo.x - zx) * (qo.x - zx)
              + (qn.y - zy) * (qn.y - zy) - (qo.y - zy) * (qo.y - zy)
              + (qn.z - zz) * (qn.z - zz) - (qo.z - zz) * (qo.z - zz)
              + (qn.w - zw) * (qn.w - zw) - (qo.w - zw) * (qo.w - zw);
#pragma unroll
      for (int off = 32; off > 0; off >>= 1) d += __shfl_down(d, off, 64);
      if (lane == 0) {
        idxi[t] = newi;
        idx_f[t] = (float)newi;
        atomicAdd(loss, d * LOSS_SCALE);
      }
    }
  }
}

// ---------------- K3: proj_out MFMA (transposed, 2-product) -------------------
// A = W_out rows (hi only), B = gathered cb hi/lo; out = A.(Bh+Bl).
__global__ __launch_bounds__(256, 4) void k_proj_out_mfma(
    const short* __restrict__ wo_hi,
    const short* __restrict__ cb_hi, const short* __restrict__ cb_lo,
    const int* __restrict__ idxi, const float* __restrict__ bout,
    float* __restrict__ out) {
  __shared__ short lds_s[3 * 128 * 32];          // 24 KB
  char* ldsc = (char*)lds_s;
  const int tid = threadIdx.x;
  const int w = tid >> 6, lane = tid & 63;
  const int quad = lane >> 4, l16 = lane & 15;
  const int wm = w >> 1, wn = w & 1;
  const int tok0 = blockIdx.x * 128;
  const int din0 = blockIdx.y * 128;

  const int uA = (w << 6) + lane, uB = uA + 256;
  const int tA = uA >> 2, pA = uA & 3, qA = pA ^ ((tA >> 1) & 3);
  const int tB = uB >> 2, pB = uB & 3, qB = pB ^ ((tB >> 1) & 3);
  const short* gAh0 = wo_hi + (size_t)(din0 + tA) * CDIM + qA * 8;
  const short* gAh1 = wo_hi + (size_t)(din0 + tB) * CDIM + qB * 8;
  const int iA = idxi[tok0 + tA];
  const int iB = idxi[tok0 + tB];
  const short* gBh0 = cb_hi + (size_t)iA * CDIM + qA * 8;
  const short* gBh1 = cb_hi + (size_t)iB * CDIM + qB * 8;
  const short* gBl0 = cb_lo + (size_t)iA * CDIM + qA * 8;
  const short* gBl1 = cb_lo + (size_t)iB * CDIM + qB * 8;

  int aoffs[4], boffs[4];
#pragma unroll
  for (int mi = 0; mi < 4; ++mi) {
    const int t = wm * 64 + mi * 16 + l16;
    aoffs[mi] = t * 64 + (quad ^ ((t >> 1) & 3)) * 16;
  }
#pragma unroll
  for (int ni = 0; ni < 4; ++ni) {
    const int t = wn * 64 + ni * 16 + l16;
    boffs[ni] = 8192 + t * 64 + (quad ^ ((t >> 1) & 3)) * 16;
  }

  f32x4 acc[4][4];
#pragma unroll
  for (int mi = 0; mi < 4; ++mi)
#pragma unroll
    for (int ni = 0; ni < 4; ++ni) acc[mi][ni] = (f32x4){0.f, 0.f, 0.f, 0.f};

  for (int kb = 0; kb < CDIM; kb += 32) {
    __syncthreads();
    GLL16(gAh0 + kb, ldsc + ((0 * 4 + w) << 10));
    GLL16(gAh1 + kb, ldsc + ((1 * 4 + w) << 10));
    GLL16(gBh0 + kb, ldsc + ((2 * 4 + w) << 10));
    GLL16(gBh1 + kb, ldsc + ((3 * 4 + w) << 10));
    GLL16(gBl0 + kb, ldsc + ((4 * 4 + w) << 10));
    GLL16(gBl1 + kb, ldsc + ((5 * 4 + w) << 10));
    __syncthreads();
    bf16x8 ah[4], bh[4], bl[4];
#pragma unroll
    for (int mi = 0; mi < 4; ++mi)
      ah[mi] = *(const bf16x8*)(ldsc + aoffs[mi]);
#pragma unroll
    for (int ni = 0; ni < 4; ++ni) {
      bh[ni] = *(const bf16x8*)(ldsc + boffs[ni]);
      bl[ni] = *(const bf16x8*)(ldsc + 8192 + boffs[ni]);
    }
#pragma unroll
    for (int mi = 0; mi < 4; ++mi)
#pragma unroll
      for (int ni = 0; ni < 4; ++ni) {
        f32x4 c = acc[mi][ni];
        c = __builtin_amdgcn_mfma_f32_16x16x32_bf16(ah[mi], bh[ni], c, 0, 0, 0);
        c = __builtin_amdgcn_mfma_f32_16x16x32_bf16(ah[mi], bl[ni], c, 0, 0, 0);
        acc[mi][ni] = c;
      }
  }
  const int b = tok0 >> 10;
  const int hwb = tok0 & (HW - 1);
  float* ob = out + (size_t)b * DIN * HW;
#pragma unroll
  for (int mi = 0; mi < 4; ++mi)
#pragma unroll
    for (int r = 0; r < 4; ++r) {
      const int din = din0 + wm * 64 + mi * 16 + quad * 4 + r;
      const float bb = bout[din];
#pragma unroll
      for (int ni = 0; ni < 4; ++ni) {
        const int hw = hwb + wn * 64 + ni * 16 + l16;
        ob[(size_t)din * HW + hw] = acc[mi][ni][r] + bb;
      }
    }
}

extern "C" void kernel_launch(void* const* d_in, const int* in_sizes, int n_in,
                              void* d_out, int out_size, void* d_ws, size_t ws_size,
                              hipStream_t stream) {
  const float* x    = (const float*)d_in[0];
  const float* Win  = (const float*)d_in[1];
  const float* bin  = (const float*)d_in[2];
  const float* Wout = (const float*)d_in[3];
  const float* bout = (const float*)d_in[4];
  const float* cb   = (const float*)d_in[5];

  float* out   = (float*)d_out;
  float* idx_f = out + OUT_ELEMS;
  float* loss  = out + OUT_ELEMS + NTOK;

  char* w = (char*)d_ws;
  size_t off = 0;
  short* z_hi  = (short*)(w + off); off += (size_t)NTOK * CDIM * 2;
  short* z_lo  = (short*)(w + off); off += (size_t)NTOK * CDIM * 2;
  short* cb_hi = (short*)(w + off); off += (size_t)KCODES * CDIM * 2;
  short* cb_lo = (short*)(w + off); off += (size_t)KCODES * CDIM * 2;
  short* xT_hi = (short*)(w + off); off += (size_t)NTOK * DIN * 2;
  short* xT_lo = (short*)(w + off); off += (size_t)NTOK * DIN * 2;
  short* wi_hi = (short*)(w + off); off += (size_t)CDIM * DIN * 2;
  short* wi_lo = (short*)(w + off); off += (size_t)CDIM * DIN * 2;
  short* wo_hi = (short*)(w + off); off += (size_t)DIN * CDIM * 2;
  float* ee    = (float*)(w + off); off += (size_t)KCODES * 4;
  int*   idxi  = (int*)(w + off);   off += (size_t)NTOK * 4;
  float* pmv   = (float*)(w + off); off += (size_t)NPART * NTOK * 4;
  int*   pmi   = (int*)(w + off);   off += (size_t)NPART * NTOK * 4;
  float* psv   = (float*)(w + off); off += (size_t)NPART * NTOK * 4;
  int*   rlist = (int*)(w + off);   off += (size_t)MAXR * 4;
  int*   rcount= (int*)(w + off);   off += 256;
  double* slotv= (double*)(w + off);off += (size_t)MAXR * RCHUNK * 8;
  int*   sloti = (int*)(w + off);   off += (size_t)MAXR * RCHUNK * 4;

  k_prep        <<<dim3(PREP_CB_BLKS + PREP_W_BLKS + PREP_X_BLKS),
                   dim3(256), 0, stream>>>(cb, Win, Wout, x, cb_hi, cb_lo, ee,
                                           wi_hi, wi_lo, wo_hi,
                                           xT_hi, xT_lo, loss, rcount);
  k_proj_in_mfma<<<dim3(NTOK / 128, CDIM / 128), dim3(256), 0, stream>>>(
      xT_hi, xT_lo, wi_hi, wi_lo, bin, z_hi, z_lo);
  k_argmin_mfma <<<dim3(NTOK / 128, NSTRIP), dim3(256), 0, stream>>>(
      z_hi, cb_hi, cb_lo, ee, pmv, pmi, psv);
  k_merge_loss  <<<dim3(NTOK / 4), dim3(256), 0, stream>>>(
      pmv, pmi, psv, z_hi, z_lo, cb, idxi, idx_f, rlist, rcount, loss);
  k_rescue_chunk<<<dim3(RBLOCKS), dim3(256), 0, stream>>>(
      z_hi, z_lo, cb, rlist, rcount, slotv, sloti);
  k_rescue_fin  <<<dim3(1), dim3(256), 0, stream>>>(
      slotv, sloti, rlist, rcount, z_hi, z_lo, cb, idxi, idx_f, loss);
  k_proj_out_mfma<<<dim3(NTOK / 128, DIN / 128), dim3(256), 0, stream>>>(
      wo_hi, cb_hi, cb_lo, idxi, bout, out);
}

// Round 9
// 472.727 us; speedup vs baseline: 3.9910x; 3.9910x over previous
//
#include <hip/hip_runtime.h>
#include <cfloat>
#include <cstdint>

// VQ-VAE vector quantizer forward. Round 8 (resubmit after broker timeout):
// revert argmin to validated 3-product split-bf16 (round-6 config; round-7's
// 2-product flagged ~1400 tokens for fp64 rescue -> 1.2ms rescue). Keep
// 2-product proj_out and fused prep/merge from round 7.
#define B_      16
#define DIN     512
#define HW      1024
#define CDIM    256
#define KCODES  8192
#define NTOK    (B_ * HW)            // 16384
#define OUT_ELEMS (B_ * DIN * HW)    // 8388608
#define GAP_EPS 1e-3f
#define NSTRIP  8
#define NPART   (NSTRIP * 2)
#define CPS     (KCODES / NSTRIP)    // 1024
#define MAXR    4096
#define RCHUNK  32
#define RBLOCKS 2048
#define LOSS_SCALE (1.0f / ((float)NTOK * (float)CDIM))

typedef __attribute__((ext_vector_type(8))) short bf16x8;
typedef __attribute__((ext_vector_type(4))) float f32x4;

static __device__ __forceinline__ short f2bf(float f) {
  unsigned u = __builtin_bit_cast(unsigned, f);
  u += 0x7FFFu + ((u >> 16) & 1u);           // RNE
  return (short)(u >> 16);
}
static __device__ __forceinline__ float bf2f(short h) {
  unsigned u = ((unsigned)(unsigned short)h) << 16;
  return __builtin_bit_cast(float, u);
}

#define GLL16(gsrc, ldst)                                                      \
  __builtin_amdgcn_global_load_lds(                                            \
      (const __attribute__((address_space(1))) unsigned int*)(gsrc),           \
      (__attribute__((address_space(3))) unsigned int*)(ldst), 16, 0, 0)

// ---------------- K0: fused prep: cb hi/lo + ee | W hi/lo | xT hi/lo ---------
#define PREP_CB_BLKS 2048
#define PREP_W_BLKS  128
#define PREP_X_BLKS  2048
__global__ __launch_bounds__(256) void k_prep(
    const float* __restrict__ cb, const float* __restrict__ Win,
    const float* __restrict__ Wout, const float* __restrict__ x,
    short* __restrict__ cb_hi, short* __restrict__ cb_lo, float* __restrict__ ee,
    short* __restrict__ wi_hi, short* __restrict__ wi_lo,
    short* __restrict__ wo_hi,
    short* __restrict__ xT_hi, short* __restrict__ xT_lo,
    float* __restrict__ loss, int* __restrict__ rcount) {
  __shared__ float T[64][65];
  const int blk = blockIdx.x;
  const int tid = threadIdx.x;
  if (blk == 0 && tid < 2) {
    if (tid == 0) *loss = 0.0f; else *rcount = 0;
  }
  if (blk < PREP_CB_BLKS) {
    const int wid = (blk * 256 + tid) >> 6;
    const int lane = tid & 63;
    const float4 v = *(const float4*)(cb + (size_t)wid * CDIM + lane * 4);
    float s = v.x * v.x + v.y * v.y + v.z * v.z + v.w * v.w;
    short4 h, l;
    h.x = f2bf(v.x); l.x = f2bf(v.x - bf2f(h.x));
    h.y = f2bf(v.y); l.y = f2bf(v.y - bf2f(h.y));
    h.z = f2bf(v.z); l.z = f2bf(v.z - bf2f(h.z));
    h.w = f2bf(v.w); l.w = f2bf(v.w - bf2f(h.w));
    *(short4*)(cb_hi + (size_t)wid * CDIM + lane * 4) = h;
    *(short4*)(cb_lo + (size_t)wid * CDIM + lane * 4) = l;
#pragma unroll
    for (int off = 32; off > 0; off >>= 1) s += __shfl_down(s, off, 64);
    if (lane == 0) ee[wid] = s;
  } else if (blk < PREP_CB_BLKS + PREP_W_BLKS) {
    const int i = ((blk - PREP_CB_BLKS) * 256 + tid) * 4;
    {
      const float4 v = *(const float4*)(Win + i);
      short4 h, l;
      h.x = f2bf(v.x); l.x = f2bf(v.x - bf2f(h.x));
      h.y = f2bf(v.y); l.y = f2bf(v.y - bf2f(h.y));
      h.z = f2bf(v.z); l.z = f2bf(v.z - bf2f(h.z));
      h.w = f2bf(v.w); l.w = f2bf(v.w - bf2f(h.w));
      *(short4*)(wi_hi + i) = h; *(short4*)(wi_lo + i) = l;
    }
    {
      const float4 v = *(const float4*)(Wout + i);
      short4 h;
      h.x = f2bf(v.x); h.y = f2bf(v.y); h.z = f2bf(v.z); h.w = f2bf(v.w);
      *(short4*)(wo_hi + i) = h;
    }
  } else {
    const int id = blk - PREP_CB_BLKS - PREP_W_BLKS;
    const int xb = id & 255, yb = id >> 8;
    const int b = xb >> 4;
    const int hw0 = (xb & 15) * 64;
    const int din0 = yb * 64;
    {
      const int r = tid >> 2;
      const int c = tid & 3;
      const float* src = x + ((size_t)b * DIN + din0 + r) * HW + hw0 + c * 16;
#pragma unroll
      for (int j = 0; j < 4; ++j) {
        const float4 v = *(const float4*)(src + j * 4);
        T[r][c * 16 + j * 4 + 0] = v.x;
        T[r][c * 16 + j * 4 + 1] = v.y;
        T[r][c * 16 + j * 4 + 2] = v.z;
        T[r][c * 16 + j * 4 + 3] = v.w;
      }
    }
    __syncthreads();
    {
      const int tt = tid & 63;
      const int c2 = tid >> 6;
      short h[16], l[16];
#pragma unroll
      for (int j = 0; j < 16; ++j) {
        const float f = T[c2 * 16 + j][tt];
        h[j] = f2bf(f); l[j] = f2bf(f - bf2f(h[j]));
      }
      const size_t base = ((size_t)b * HW + hw0 + tt) * DIN + din0 + c2 * 16;
      *(bf16x8*)(xT_hi + base)     = *(bf16x8*)&h[0];
      *(bf16x8*)(xT_hi + base + 8) = *(bf16x8*)&h[8];
      *(bf16x8*)(xT_lo + base)     = *(bf16x8*)&l[0];
      *(bf16x8*)(xT_lo + base + 8) = *(bf16x8*)&l[8];
    }
  }
}

// ---------------- K1: proj_in MFMA: z = xT @ Win^T + b_in (3-product) ---------
__global__ __launch_bounds__(256, 2) void k_proj_in_mfma(
    const short* __restrict__ xT_hi, const short* __restrict__ xT_lo,
    const short* __restrict__ wi_hi, const short* __restrict__ wi_lo,
    const float* __restrict__ bin,
    short* __restrict__ z_hi, short* __restrict__ z_lo) {
  __shared__ short lds_s[4 * 128 * 32];
  char* ldsc = (char*)lds_s;
  const int tid = threadIdx.x;
  const int w = tid >> 6, lane = tid & 63;
  const int quad = lane >> 4, l16 = lane & 15;
  const int wm = w >> 1, wn = w & 1;
  const int tok0 = blockIdx.x * 128;
  const int cd0 = blockIdx.y * 128;

  const int uA = (w << 6) + lane, uB = uA + 256;
  const int tA = uA >> 2, pA = uA & 3, qA = pA ^ ((tA >> 1) & 3);
  const int tB = uB >> 2, pB = uB & 3, qB = pB ^ ((tB >> 1) & 3);
  const int offA = tA * DIN + qA * 8;
  const int offB = tB * DIN + qB * 8;
  const short* gAh0 = xT_hi + (size_t)tok0 * DIN + offA;
  const short* gAh1 = xT_hi + (size_t)tok0 * DIN + offB;
  const short* gAl0 = xT_lo + (size_t)tok0 * DIN + offA;
  const short* gAl1 = xT_lo + (size_t)tok0 * DIN + offB;
  const short* gBh0 = wi_hi + (size_t)cd0 * DIN + offA;
  const short* gBh1 = wi_hi + (size_t)cd0 * DIN + offB;
  const short* gBl0 = wi_lo + (size_t)cd0 * DIN + offA;
  const short* gBl1 = wi_lo + (size_t)cd0 * DIN + offB;

  int aoffs[4], boffs[4];
#pragma unroll
  for (int mi = 0; mi < 4; ++mi) {
    const int t = wm * 64 + mi * 16 + l16;
    aoffs[mi] = t * 64 + (quad ^ ((t >> 1) & 3)) * 16;
  }
#pragma unroll
  for (int ni = 0; ni < 4; ++ni) {
    const int t = wn * 64 + ni * 16 + l16;
    boffs[ni] = 16384 + t * 64 + (quad ^ ((t >> 1) & 3)) * 16;
  }

  f32x4 acc[4][4];
#pragma unroll
  for (int mi = 0; mi < 4; ++mi)
#pragma unroll
    for (int ni = 0; ni < 4; ++ni) acc[mi][ni] = (f32x4){0.f, 0.f, 0.f, 0.f};

  for (int kb = 0; kb < DIN; kb += 32) {
    __syncthreads();
    GLL16(gAh0 + kb, ldsc + ((0 * 4 + w) << 10));
    GLL16(gAh1 + kb, ldsc + ((1 * 4 + w) << 10));
    GLL16(gAl0 + kb, ldsc + ((2 * 4 + w) << 10));
    GLL16(gAl1 + kb, ldsc + ((3 * 4 + w) << 10));
    GLL16(gBh0 + kb, ldsc + ((4 * 4 + w) << 10));
    GLL16(gBh1 + kb, ldsc + ((5 * 4 + w) << 10));
    GLL16(gBl0 + kb, ldsc + ((6 * 4 + w) << 10));
    GLL16(gBl1 + kb, ldsc + ((7 * 4 + w) << 10));
    __syncthreads();
    bf16x8 ah[4], al[4], bh[4], bl[4];
#pragma unroll
    for (int mi = 0; mi < 4; ++mi) {
      ah[mi] = *(const bf16x8*)(ldsc + aoffs[mi]);
      al[mi] = *(const bf16x8*)(ldsc + 8192 + aoffs[mi]);
    }
#pragma unroll
    for (int ni = 0; ni < 4; ++ni) {
      bh[ni] = *(const bf16x8*)(ldsc + boffs[ni]);
      bl[ni] = *(const bf16x8*)(ldsc + 8192 + boffs[ni]);
    }
#pragma unroll
    for (int mi = 0; mi < 4; ++mi)
#pragma unroll
      for (int ni = 0; ni < 4; ++ni) {
        f32x4 c = acc[mi][ni];
        c = __builtin_amdgcn_mfma_f32_16x16x32_bf16(ah[mi], bh[ni], c, 0, 0, 0);
        c = __builtin_amdgcn_mfma_f32_16x16x32_bf16(ah[mi], bl[ni], c, 0, 0, 0);
        c = __builtin_amdgcn_mfma_f32_16x16x32_bf16(al[mi], bh[ni], c, 0, 0, 0);
        acc[mi][ni] = c;
      }
  }
  float bv[4];
#pragma unroll
  for (int ni = 0; ni < 4; ++ni) bv[ni] = bin[cd0 + wn * 64 + ni * 16 + l16];
#pragma unroll
  for (int mi = 0; mi < 4; ++mi)
#pragma unroll
    for (int r = 0; r < 4; ++r) {
      const int t = tok0 + wm * 64 + mi * 16 + quad * 4 + r;
#pragma unroll
      for (int ni = 0; ni < 4; ++ni) {
        const int cd = cd0 + wn * 64 + ni * 16 + l16;
        const float o = acc[mi][ni][r] + bv[ni];
        const short h = f2bf(o);
        z_hi[(size_t)t * CDIM + cd] = h;
        z_lo[(size_t)t * CDIM + cd] = f2bf(o - bf2f(h));
      }
    }
}

// ---------------- K2: MFMA distance GEMM + argmin (3-product, validated) ------
__global__ __launch_bounds__(256, 2) void k_argmin_mfma(
    const short* __restrict__ z_hi, const short* __restrict__ z_lo,
    const short* __restrict__ cb_hi, const short* __restrict__ cb_lo,
    const float* __restrict__ ee,
    float* __restrict__ pmv, int* __restrict__ pmi, float* __restrict__ psv) {
  __shared__ short lds_s[4 * 128 * 32];          // 32 KB
  char* ldsc = (char*)lds_s;
  const int tid = threadIdx.x;
  const int w = tid >> 6, lane = tid & 63;
  const int quad = lane >> 4, l16 = lane & 15;
  const int wm = w >> 1, wn = w & 1;
  const int tok0 = blockIdx.x * 128;
  const int cbase = blockIdx.y * CPS;

  const int uA = (w << 6) + lane, uB = uA + 256;
  const int tA = uA >> 2, pA = uA & 3, qA = pA ^ ((tA >> 1) & 3);
  const int tB = uB >> 2, pB = uB & 3, qB = pB ^ ((tB >> 1) & 3);
  const int offA = tA * CDIM + qA * 8;
  const int offB = tB * CDIM + qB * 8;
  const short* gAh0 = z_hi + (size_t)tok0 * CDIM + offA;
  const short* gAh1 = z_hi + (size_t)tok0 * CDIM + offB;
  const short* gAl0 = z_lo + (size_t)tok0 * CDIM + offA;
  const short* gAl1 = z_lo + (size_t)tok0 * CDIM + offB;

  int aoffs[4], boffs[4];
#pragma unroll
  for (int mi = 0; mi < 4; ++mi) {
    const int t = wm * 64 + mi * 16 + l16;
    aoffs[mi] = t * 64 + (quad ^ ((t >> 1) & 3)) * 16;
  }
#pragma unroll
  for (int ni = 0; ni < 4; ++ni) {
    const int t = wn * 64 + ni * 16 + l16;
    boffs[ni] = 16384 + t * 64 + (quad ^ ((t >> 1) & 3)) * 16;
  }

  float mv[16], sv[16]; int bidx[16];
#pragma unroll
  for (int j = 0; j < 16; ++j) { mv[j] = FLT_MAX; sv[j] = FLT_MAX; bidx[j] = 0; }

  for (int ct = 0; ct < CPS / 128; ++ct) {
    const int ctile = cbase + ct * 128;
    const short* gBh0 = cb_hi + (size_t)ctile * CDIM + offA;
    const short* gBh1 = cb_hi + (size_t)ctile * CDIM + offB;
    const short* gBl0 = cb_lo + (size_t)ctile * CDIM + offA;
    const short* gBl1 = cb_lo + (size_t)ctile * CDIM + offB;
    f32x4 acc[4][4];
#pragma unroll
    for (int mi = 0; mi < 4; ++mi)
#pragma unroll
      for (int ni = 0; ni < 4; ++ni) acc[mi][ni] = (f32x4){0.f, 0.f, 0.f, 0.f};

    for (int kb = 0; kb < CDIM; kb += 32) {
      __syncthreads();
      GLL16(gAh0 + kb, ldsc + ((0 * 4 + w) << 10));
      GLL16(gAh1 + kb, ldsc + ((1 * 4 + w) << 10));
      GLL16(gAl0 + kb, ldsc + ((2 * 4 + w) << 10));
      GLL16(gAl1 + kb, ldsc + ((3 * 4 + w) << 10));
      GLL16(gBh0 + kb, ldsc + ((4 * 4 + w) << 10));
      GLL16(gBh1 + kb, ldsc + ((5 * 4 + w) << 10));
      GLL16(gBl0 + kb, ldsc + ((6 * 4 + w) << 10));
      GLL16(gBl1 + kb, ldsc + ((7 * 4 + w) << 10));
      __syncthreads();
      bf16x8 ah[4], al[4], bh[4], bl[4];
#pragma unroll
      for (int mi = 0; mi < 4; ++mi) {
        ah[mi] = *(const bf16x8*)(ldsc + aoffs[mi]);
        al[mi] = *(const bf16x8*)(ldsc + 8192 + aoffs[mi]);
      }
#pragma unroll
      for (int ni = 0; ni < 4; ++ni) {
        bh[ni] = *(const bf16x8*)(ldsc + boffs[ni]);
        bl[ni] = *(const bf16x8*)(ldsc + 8192 + boffs[ni]);
      }
#pragma unroll
      for (int mi = 0; mi < 4; ++mi)
#pragma unroll
        for (int ni = 0; ni < 4; ++ni) {
          f32x4 c = acc[mi][ni];
          c = __builtin_amdgcn_mfma_f32_16x16x32_bf16(ah[mi], bh[ni], c, 0, 0, 0);
          c = __builtin_amdgcn_mfma_f32_16x16x32_bf16(ah[mi], bl[ni], c, 0, 0, 0);
          c = __builtin_amdgcn_mfma_f32_16x16x32_bf16(al[mi], bh[ni], c, 0, 0, 0);
          acc[mi][ni] = c;
        }
    }
    float eev[4];
#pragma unroll
    for (int ni = 0; ni < 4; ++ni) eev[ni] = ee[ctile + wn * 64 + ni * 16 + l16];
    const int cb2 = ctile + wn * 64 + l16;
#pragma unroll
    for (int mi = 0; mi < 4; ++mi)
#pragma unroll
      for (int r = 0; r < 4; ++r) {
        const int j = mi * 4 + r;
#pragma unroll
        for (int ni = 0; ni < 4; ++ni) {
          const float s = fmaf(-2.0f, acc[mi][ni][r], eev[ni]);
          sv[j] = fminf(sv[j], fmaxf(mv[j], s));
          if (s < mv[j]) { mv[j] = s; bidx[j] = cb2 + ni * 16; }
        }
      }
  }
#pragma unroll
  for (int off = 1; off < 16; off <<= 1) {
#pragma unroll
    for (int j = 0; j < 16; ++j) {
      const float ov = __shfl_xor(mv[j], off, 64);
      const int   oi = __shfl_xor(bidx[j], off, 64);
      const float os = __shfl_xor(sv[j], off, 64);
      const float snew = fminf(fminf(sv[j], os), fmaxf(mv[j], ov));
      if (ov < mv[j] || (ov == mv[j] && oi < bidx[j])) { mv[j] = ov; bidx[j] = oi; }
      sv[j] = snew;
    }
  }
  if (l16 == 0) {
    const int strip = blockIdx.y * 2 + wn;
#pragma unroll
    for (int j = 0; j < 16; ++j) {
      const int mi = j >> 2, r = j & 3;
      const int t = tok0 + wm * 64 + mi * 16 + quad * 4 + r;
      const size_t o = (size_t)strip * NTOK + t;
      pmv[o] = mv[j]; pmi[o] = bidx[j]; psv[o] = sv[j];
    }
  }
}

// ---------------- K2b: merge 16 partials + provisional loss (fused) -----------
__global__ __launch_bounds__(256) void k_merge_loss(
    const float* __restrict__ pmv, const int* __restrict__ pmi,
    const float* __restrict__ psv,
    const short* __restrict__ z_hi, const short* __restrict__ z_lo,
    const float* __restrict__ cb,
    int* __restrict__ idxi, float* __restrict__ idx_f,
    int* __restrict__ rlist, int* __restrict__ rcount,
    float* __restrict__ loss) {
  __shared__ float lpart[4];
  const int tid = threadIdx.x;
  const int wv = tid >> 6, lane = tid & 63;
  const int t = blockIdx.x * 4 + wv;
  float mv = FLT_MAX, sv = FLT_MAX; int mi = 0x7fffffff;
  if (lane < NPART) {
    mv = pmv[(size_t)lane * NTOK + t];
    mi = pmi[(size_t)lane * NTOK + t];
    sv = psv[(size_t)lane * NTOK + t];
  }
#pragma unroll
  for (int off = 1; off < 16; off <<= 1) {
    const float ov = __shfl_xor(mv, off, 64);
    const int   oi = __shfl_xor(mi, off, 64);
    const float os = __shfl_xor(sv, off, 64);
    const float snew = fminf(fminf(sv, os), fmaxf(mv, ov));
    if (ov < mv || (ov == mv && oi < mi)) { mv = ov; mi = oi; }
    sv = snew;
  }
  const int mif = __shfl(mi, 0, 64);
  const short4 h4 = *(const short4*)(z_hi + (size_t)t * CDIM + lane * 4);
  const short4 l4 = *(const short4*)(z_lo + (size_t)t * CDIM + lane * 4);
  const float4 qv = *(const float4*)(cb + (size_t)mif * CDIM + lane * 4);
  const float dx = qv.x - (bf2f(h4.x) + bf2f(l4.x));
  const float dy = qv.y - (bf2f(h4.y) + bf2f(l4.y));
  const float dz = qv.z - (bf2f(h4.z) + bf2f(l4.z));
  const float dw = qv.w - (bf2f(h4.w) + bf2f(l4.w));
  float s = dx * dx + dy * dy + dz * dz + dw * dw;
#pragma unroll
  for (int off = 32; off > 0; off >>= 1) s += __shfl_down(s, off, 64);
  if (lane == 0) {
    idxi[t] = mif;
    idx_f[t] = (float)mif;
    lpart[wv] = s;
    if (sv - mv < GAP_EPS) {
      const int pos = atomicAdd(rcount, 1);
      if (pos < MAXR) rlist[pos] = t;
    }
  }
  __syncthreads();
  if (tid == 0) {
    atomicAdd(loss, (lpart[0] + lpart[1] + lpart[2] + lpart[3]) * LOSS_SCALE);
  }
}

// ---------------- K2c: chunked fp64 rescore -----------------------------------
__global__ __launch_bounds__(256) void k_rescue_chunk(
    const short* __restrict__ z_hi, const short* __restrict__ z_lo,
    const float* __restrict__ cb,
    const int* __restrict__ rlist, const int* __restrict__ rcount,
    double* __restrict__ slotv, int* __restrict__ sloti) {
  const int cnt0 = *rcount;
  const int cnt = cnt0 < MAXR ? cnt0 : MAXR;
  const int li0 = blockIdx.x >> 5;
  const int chunk = blockIdx.x & (RCHUNK - 1);
  if (li0 >= cnt) return;
  __shared__ float zrow[CDIM];
  __shared__ double rv[256];
  __shared__ int ri[256];
  const int tid = threadIdx.x;
  for (int li = li0; li < cnt; li += RBLOCKS / RCHUNK) {
    const int t = rlist[li];
    zrow[tid] = bf2f(z_hi[(size_t)t * CDIM + tid]) + bf2f(z_lo[(size_t)t * CDIM + tid]);
    __syncthreads();
    const int k = chunk * 256 + tid;
    const float* e = cb + (size_t)k * CDIM;
    double s0 = 0.0, s1 = 0.0, s2 = 0.0, s3 = 0.0;
    for (int c = 0; c < CDIM; c += 4) {
      const double d0 = (double)zrow[c]     - (double)e[c];
      const double d1 = (double)zrow[c + 1] - (double)e[c + 1];
      const double d2 = (double)zrow[c + 2] - (double)e[c + 2];
      const double d3 = (double)zrow[c + 3] - (double)e[c + 3];
      s0 += d0 * d0; s1 += d1 * d1; s2 += d2 * d2; s3 += d3 * d3;
    }
    rv[tid] = (s0 + s1) + (s2 + s3);
    ri[tid] = k;
    __syncthreads();
    for (int off = 128; off > 0; off >>= 1) {
      if (tid < off) {
        if (rv[tid + off] < rv[tid] ||
            (rv[tid + off] == rv[tid] && ri[tid + off] < ri[tid])) {
          rv[tid] = rv[tid + off]; ri[tid] = ri[tid + off];
        }
      }
      __syncthreads();
    }
    if (tid == 0) {
      slotv[(size_t)li * RCHUNK + chunk] = rv[0];
      sloti[(size_t)li * RCHUNK + chunk] = ri[0];
    }
    __syncthreads();
  }
}

// ---------------- K2d: fold chunk slots, patch indices + loss delta -----------
__global__ __launch_bounds__(256) void k_rescue_fin(
    const double* __restrict__ slotv, const int* __restrict__ sloti,
    const int* __restrict__ rlist, const int* __restrict__ rcount,
    const short* __restrict__ z_hi, const short* __restrict__ z_lo,
    const float* __restrict__ cb,
    int* __restrict__ idxi, float* __restrict__ idx_f, float* __restrict__ loss) {
  const int cnt0 = *rcount;
  const int cnt = cnt0 < MAXR ? cnt0 : MAXR;
  const int tid = threadIdx.x;
  const int wv = tid >> 6, lane = tid & 63;
  for (int li = wv; li < cnt; li += 4) {
    double bv = 1e300; int bx = 0x7fffffff;
    if (lane < RCHUNK) {
      bv = slotv[(size_t)li * RCHUNK + lane];
      bx = sloti[(size_t)li * RCHUNK + lane];
    }
#pragma unroll
    for (int off = 1; off < 32; off <<= 1) {
      const double ov = __shfl_xor(bv, off, 64);
      const int   oi = __shfl_xor(bx, off, 64);
      if (ov < bv || (ov == bv && oi < bx)) { bv = ov; bx = oi; }
    }
    const int newi = __shfl(bx, 0, 64);
    const int t = rlist[li];
    const int oldi = idxi[t];
    if (newi != oldi) {
      const short4 h4 = *(const short4*)(z_hi + (size_t)t * CDIM + lane * 4);
      const short4 l4 = *(const short4*)(z_lo + (size_t)t * CDIM + lane * 4);
      const float4 qn = *(const float4*)(cb + (size_t)newi * CDIM + lane * 4);
      const float4 qo = *(const float4*)(cb + (size_t)oldi * CDIM + lane * 4);
      const float zx = bf2f(h4.x) + bf2f(l4.x);
      const float zy = bf2f(h4.y) + bf2f(l4.y);
      const float zz = bf2f(h4.z) + bf2f(l4.z);
      const float zw = bf2f(h4.w) + bf2f(l4.w);
      float d = (qn.x - zx) * (qn.x - zx) - (qo.x - zx) * (qo.x - zx)
              + (qn.y - zy) * (qn.y - zy) - (qo.y - zy) * (qo.y - zy)
              + (qn.z - zz) * (qn.z - zz) - (qo.z - zz) * (qo.z - zz)
              + (qn.w - zw) * (qn.w - zw) - (qo.w - zw) * (qo.w - zw);
#pragma unroll
      for (int off = 32; off > 0; off >>= 1) d += __shfl_down(d, off, 64);
      if (lane == 0) {
        idxi[t] = newi;
        idx_f[t] = (float)newi;
        atomicAdd(loss, d * LOSS_SCALE);
      }
    }
  }
}

// ---------------- K3: proj_out MFMA (transposed, 2-product) -------------------
__global__ __launch_bounds__(256, 4) void k_proj_out_mfma(
    const short* __restrict__ wo_hi,
    const short* __restrict__ cb_hi, const short* __restrict__ cb_lo,
    const int* __restrict__ idxi, const float* __restrict__ bout,
    float* __restrict__ out) {
  __shared__ short lds_s[3 * 128 * 32];          // 24 KB
  char* ldsc = (char*)lds_s;
  const int tid = threadIdx.x;
  const int w = tid >> 6, lane = tid & 63;
  const int quad = lane >> 4, l16 = lane & 15;
  const int wm = w >> 1, wn = w & 1;
  const int tok0 = blockIdx.x * 128;
  const int din0 = blockIdx.y * 128;

  const int uA = (w << 6) + lane, uB = uA + 256;
  const int tA = uA >> 2, pA = uA & 3, qA = pA ^ ((tA >> 1) & 3);
  const int tB = uB >> 2, pB = uB & 3, qB = pB ^ ((tB >> 1) & 3);
  const short* gAh0 = wo_hi + (size_t)(din0 + tA) * CDIM + qA * 8;
  const short* gAh1 = wo_hi + (size_t)(din0 + tB) * CDIM + qB * 8;
  const int iA = idxi[tok0 + tA];
  const int iB = idxi[tok0 + tB];
  const short* gBh0 = cb_hi + (size_t)iA * CDIM + qA * 8;
  const short* gBh1 = cb_hi + (size_t)iB * CDIM + qB * 8;
  const short* gBl0 = cb_lo + (size_t)iA * CDIM + qA * 8;
  const short* gBl1 = cb_lo + (size_t)iB * CDIM + qB * 8;

  int aoffs[4], boffs[4];
#pragma unroll
  for (int mi = 0; mi < 4; ++mi) {
    const int t = wm * 64 + mi * 16 + l16;
    aoffs[mi] = t * 64 + (quad ^ ((t >> 1) & 3)) * 16;
  }
#pragma unroll
  for (int ni = 0; ni < 4; ++ni) {
    const int t = wn * 64 + ni * 16 + l16;
    boffs[ni] = 8192 + t * 64 + (quad ^ ((t >> 1) & 3)) * 16;
  }

  f32x4 acc[4][4];
#pragma unroll
  for (int mi = 0; mi < 4; ++mi)
#pragma unroll
    for (int ni = 0; ni < 4; ++ni) acc[mi][ni] = (f32x4){0.f, 0.f, 0.f, 0.f};

  for (int kb = 0; kb < CDIM; kb += 32) {
    __syncthreads();
    GLL16(gAh0 + kb, ldsc + ((0 * 4 + w) << 10));
    GLL16(gAh1 + kb, ldsc + ((1 * 4 + w) << 10));
    GLL16(gBh0 + kb, ldsc + ((2 * 4 + w) << 10));
    GLL16(gBh1 + kb, ldsc + ((3 * 4 + w) << 10));
    GLL16(gBl0 + kb, ldsc + ((4 * 4 + w) << 10));
    GLL16(gBl1 + kb, ldsc + ((5 * 4 + w) << 10));
    __syncthreads();
    bf16x8 ah[4], bh[4], bl[4];
#pragma unroll
    for (int mi = 0; mi < 4; ++mi)
      ah[mi] = *(const bf16x8*)(ldsc + aoffs[mi]);
#pragma unroll
    for (int ni = 0; ni < 4; ++ni) {
      bh[ni] = *(const bf16x8*)(ldsc + boffs[ni]);
      bl[ni] = *(const bf16x8*)(ldsc + 8192 + boffs[ni]);
    }
#pragma unroll
    for (int mi = 0; mi < 4; ++mi)
#pragma unroll
      for (int ni = 0; ni < 4; ++ni) {
        f32x4 c = acc[mi][ni];
        c = __builtin_amdgcn_mfma_f32_16x16x32_bf16(ah[mi], bh[ni], c, 0, 0, 0);
        c = __builtin_amdgcn_mfma_f32_16x16x32_bf16(ah[mi], bl[ni], c, 0, 0, 0);
        acc[mi][ni] = c;
      }
  }
  const int b = tok0 >> 10;
  const int hwb = tok0 & (HW - 1);
  float* ob = out + (size_t)b * DIN * HW;
#pragma unroll
  for (int mi = 0; mi < 4; ++mi)
#pragma unroll
    for (int r = 0; r < 4; ++r) {
      const int din = din0 + wm * 64 + mi * 16 + quad * 4 + r;
      const float bb = bout[din];
#pragma unroll
      for (int ni = 0; ni < 4; ++ni) {
        const int hw = hwb + wn * 64 + ni * 16 + l16;
        ob[(size_t)din * HW + hw] = acc[mi][ni][r] + bb;
      }
    }
}

extern "C" void kernel_launch(void* const* d_in, const int* in_sizes, int n_in,
                              void* d_out, int out_size, void* d_ws, size_t ws_size,
                              hipStream_t stream) {
  const float* x    = (const float*)d_in[0];
  const float* Win  = (const float*)d_in[1];
  const float* bin  = (const float*)d_in[2];
  const float* Wout = (const float*)d_in[3];
  const float* bout = (const float*)d_in[4];
  const float* cb   = (const float*)d_in[5];

  float* out   = (float*)d_out;
  float* idx_f = out + OUT_ELEMS;
  float* loss  = out + OUT_ELEMS + NTOK;

  char* w = (char*)d_ws;
  size_t off = 0;
  short* z_hi  = (short*)(w + off); off += (size_t)NTOK * CDIM * 2;
  short* z_lo  = (short*)(w + off); off += (size_t)NTOK * CDIM * 2;
  short* cb_hi = (short*)(w + off); off += (size_t)KCODES * CDIM * 2;
  short* cb_lo = (short*)(w + off); off += (size_t)KCODES * CDIM * 2;
  short* xT_hi = (short*)(w + off); off += (size_t)NTOK * DIN * 2;
  short* xT_lo = (short*)(w + off); off += (size_t)NTOK * DIN * 2;
  short* wi_hi = (short*)(w + off); off += (size_t)CDIM * DIN * 2;
  short* wi_lo = (short*)(w + off); off += (size_t)CDIM * DIN * 2;
  short* wo_hi = (short*)(w + off); off += (size_t)DIN * CDIM * 2;
  float* ee    = (float*)(w + off); off += (size_t)KCODES * 4;
  int*   idxi  = (int*)(w + off);   off += (size_t)NTOK * 4;
  float* pmv   = (float*)(w + off); off += (size_t)NPART * NTOK * 4;
  int*   pmi   = (int*)(w + off);   off += (size_t)NPART * NTOK * 4;
  float* psv   = (float*)(w + off); off += (size_t)NPART * NTOK * 4;
  int*   rlist = (int*)(w + off);   off += (size_t)MAXR * 4;
  int*   rcount= (int*)(w + off);   off += 256;
  double* slotv= (double*)(w + off);off += (size_t)MAXR * RCHUNK * 8;
  int*   sloti = (int*)(w + off);   off += (size_t)MAXR * RCHUNK * 4;

  k_prep        <<<dim3(PREP_CB_BLKS + PREP_W_BLKS + PREP_X_BLKS),
                   dim3(256), 0, stream>>>(cb, Win, Wout, x, cb_hi, cb_lo, ee,
                                           wi_hi, wi_lo, wo_hi,
                                           xT_hi, xT_lo, loss, rcount);
  k_proj_in_mfma<<<dim3(NTOK / 128, CDIM / 128), dim3(256), 0, stream>>>(
      xT_hi, xT_lo, wi_hi, wi_lo, bin, z_hi, z_lo);
  k_argmin_mfma <<<dim3(NTOK / 128, NSTRIP), dim3(256), 0, stream>>>(
      z_hi, z_lo, cb_hi, cb_lo, ee, pmv, pmi, psv);
  k_merge_loss  <<<dim3(NTOK / 4), dim3(256), 0, stream>>>(
      pmv, pmi, psv, z_hi, z_lo, cb, idxi, idx_f, rlist, rcount, loss);
  k_rescue_chunk<<<dim3(RBLOCKS), dim3(256), 0, stream>>>(
      z_hi, z_lo, cb, rlist, rcount, slotv, sloti);
  k_rescue_fin  <<<dim3(1), dim3(256), 0, stream>>>(
      slotv, sloti, rlist, rcount, z_hi, z_lo, cb, idxi, idx_f, loss);
  k_proj_out_mfma<<<dim3(NTOK / 128, DIN / 128), dim3(256), 0, stream>>>(
      wo_hi, cb_hi, cb_lo, idxi, bout, out);
}